// Round 4
// baseline (124.481 us; speedup 1.0000x reference)
//
#include <hip/hip_runtime.h>
#include <hip/hip_bf16.h>

#define NATOMS 262144
#define NG     8192
#define FDIM   128
#define NELEM  118
#define EPS    1e-6f

typedef __attribute__((ext_vector_type(8))) short bf16x8;
typedef __attribute__((ext_vector_type(4))) float f32x4;

__device__ __forceinline__ unsigned short f2bf_rn(float x) {
    unsigned u = __float_as_uint(x);
    unsigned r = (u + 0x7FFFu + ((u >> 16) & 1u)) >> 16;
    return (unsigned short)r;
}
__device__ __forceinline__ float bf2f(unsigned short h) {
    return __uint_as_float((unsigned)h << 16);
}

// fast silu via v_rcp_f32 (~1 ulp; negligible vs bf16 split error)
__device__ __forceinline__ float silu_fast(float v) {
    return v * __builtin_amdgcn_rcpf(1.f + __expf(-v));
}

// truncation-based hi/lo split of two floats -> packed u32 (hi pair, lo pair)
__device__ __forceinline__ void split2(float x0, float x1,
                                       unsigned& hpack, unsigned& lpack) {
    unsigned u0 = __float_as_uint(x0), u1 = __float_as_uint(x1);
    unsigned h0m = u0 & 0xFFFF0000u, h1m = u1 & 0xFFFF0000u;
    hpack = (u0 >> 16) | h1m;
    float l0 = x0 - __uint_as_float(h0m);
    float l1 = x1 - __uint_as_float(h1m);
    lpack = (__float_as_uint(l0) >> 16) | (__float_as_uint(l1) & 0xFFFF0000u);
}

// swizzled LDS offset (u16 elements): row stride 128, 16B-granule XOR swizzle.
// Bijective per row; makes stride-row ds_read_b128 cover all 32 banks (2-way).
__device__ __forceinline__ int aoff(int row, int k) {
    return row * FDIM + ((((k >> 3) ^ row) & 15) << 3) + (k & 7);
}

// ---------------------------------------------------------------------------
// Kernel 1: T[idx][z] = softplus( dot(Wq[:,z], Wk[idx,:]) / sqrt(F) )
// ---------------------------------------------------------------------------
__global__ void table_kernel(const float* __restrict__ Wq,
                             const float* __restrict__ Wk,
                             float* __restrict__ T) {
    int p = threadIdx.x;
    if (p < 2 * NELEM) {
        int idx = p / NELEM;
        int z   = p - idx * NELEM;
        float dot = 0.f;
        #pragma unroll 8
        for (int f = 0; f < FDIM; ++f)
            dot += Wq[f * NELEM + z] * Wk[idx * FDIM + f];
        float x = dot * 0.08838834764831843f;  // 1/sqrt(128)
        T[p] = fmaxf(x, 0.f) + log1pf(expf(-fabsf(x)));
    }
}

// ---------------------------------------------------------------------------
// Kernel 1b: split W1,W2 into bf16 hi/lo (round-nearest; runs once, tiny).
// ---------------------------------------------------------------------------
__global__ void wsplit_kernel(const float* __restrict__ W1,
                              const float* __restrict__ W2,
                              unsigned short* __restrict__ Whi,
                              unsigned short* __restrict__ Wlo) {
    int i = blockIdx.x * blockDim.x + threadIdx.x;  // 0..32767
    float x = (i < FDIM * FDIM) ? W1[i] : W2[i - FDIM * FDIM];
    unsigned short h = f2bf_rn(x);
    unsigned short l = f2bf_rn(x - bf2f(h));
    Whi[i] = h;
    Wlo[i] = l;
}

// ---------------------------------------------------------------------------
// Kernel 2: recover z[n] from the one-hot rows (coalesced float4 sweep).
// ---------------------------------------------------------------------------
__global__ void zscan_kernel(const float4* __restrict__ onehot4,
                             int* __restrict__ z) {
    const int total4 = NATOMS * NELEM / 4;
    int i = blockIdx.x * blockDim.x + threadIdx.x;
    if (i >= total4) return;
    float4 v = onehot4[i];
    int base = i * 4;
    if (v.x > 0.5f) { int g = base + 0; int n = g / NELEM; z[n] = g - n * NELEM; }
    if (v.y > 0.5f) { int g = base + 1; int n = g / NELEM; z[n] = g - n * NELEM; }
    if (v.z > 0.5f) { int g = base + 2; int n = g / NELEM; z[n] = g - n * NELEM; }
    if (v.w > 0.5f) { int g = base + 3; int n = g / NELEM; z[n] = g - n * NELEM; }
}

// ---------------------------------------------------------------------------
// Kernel 3: y[n] = T[idx(g)][z[n]]; denom[g] = segment_sum(y) via wave scan.
// ---------------------------------------------------------------------------
__global__ void ydenom_kernel(const int* __restrict__ seg,
                              const float* __restrict__ psi,
                              const float* __restrict__ T,
                              const int* __restrict__ z,
                              float* __restrict__ y_out,
                              float* __restrict__ denom) {
    int n = blockIdx.x * blockDim.x + threadIdx.x;
    int g = seg[n];
    float ps = psi[g];
    int idx = ps < 0.f ? 1 : 0;
    float yv = T[idx * NELEM + z[n]];
    y_out[n] = yv;

    int lane = threadIdx.x & 63;
    float val = yv;
    #pragma unroll
    for (int d = 1; d < 64; d <<= 1) {
        float o = __shfl_up(val, (unsigned)d, 64);
        int  go = __shfl_up(g,   (unsigned)d, 64);
        if (lane >= d && go == g) val += o;
    }
    int gn = __shfl_down(g, 1u, 64);
    if (lane == 63 || gn != g) atomicAdd(&denom[g], val);
}

// ---------------------------------------------------------------------------
// Kernel 4: MFMA MLP. 128 atoms/block, 512 threads = 8 waves in a 2x4 grid.
// Wave (wr,wc) owns rows [64*wr,+64) x cols [32*wc,+32). Split-bf16:
// 3 MFMA per fp32 product. Swizzled LDS (64KB act) -> 2 blocks/CU.
// ---------------------------------------------------------------------------
__launch_bounds__(512, 4)
__global__ void mlp_kernel(const int* __restrict__ seg,
                           const float* __restrict__ psi,
                           const float* __restrict__ y_ws,
                           const float* __restrict__ denom,
                           const float* __restrict__ Wv,
                           const unsigned short* __restrict__ Whi,
                           const unsigned short* __restrict__ Wlo,
                           float* __restrict__ out) {
    __shared__ __align__(16) unsigned short Ahi[FDIM * FDIM];
    __shared__ __align__(16) unsigned short Alo[FDIM * FDIM];
    __shared__ float att_s[128];
    __shared__ int   idx_s[128];
    __shared__ float wv_s[2 * FDIM];

    int t    = threadIdx.x;
    int lane = t & 63;
    int w    = t >> 6;
    int wr   = w >> 2;
    int wc   = w & 3;
    int n0   = blockIdx.x * 128;
    int rbase = wr * 64;
    int jbase = wc * 32;

    if (t < 256) wv_s[t] = Wv[t];
    if (t >= 256 && t < 384) {
        int a = t - 256;
        int n = n0 + a;
        int g = seg[n];
        float ps = psi[g];
        idx_s[a] = ps < 0.f ? 1 : 0;
        att_s[a] = ps * y_ws[n] * __builtin_amdgcn_rcpf(denom[g] + EPS);
    }
    __syncthreads();

    // phase 1: act0[a][k] = silu(att*wv[idx][k]) -> split bf16 into LDS
    {
        int a  = t >> 2;
        int kq = (t & 3) * 32;
        float att = att_s[a];
        const float* wvp = &wv_s[idx_s[a] * FDIM + kq];
        #pragma unroll
        for (int kk = 0; kk < 32; kk += 2) {
            float s0 = silu_fast(att * wvp[kk]);
            float s1 = silu_fast(att * wvp[kk + 1]);
            unsigned hp, lp;
            split2(s0, s1, hp, lp);
            int off = aoff(a, kq + kk);   // even, pair stays in one granule
            *(unsigned*)&Ahi[off] = hp;
            *(unsigned*)&Alo[off] = lp;
        }
    }
    __syncthreads();

    int lrow = lane & 15;          // fragment row/col within a 16x16 tile
    int k0   = (lane >> 4) * 8;    // fragment k base

    f32x4 acc[4][2];

    #pragma unroll
    for (int L = 0; L < 2; ++L) {
        const unsigned short* WH = Whi + L * FDIM * FDIM;
        const unsigned short* WL = Wlo + L * FDIM * FDIM;

        #pragma unroll
        for (int mt = 0; mt < 4; ++mt)
            #pragma unroll
            for (int jt = 0; jt < 2; ++jt)
                acc[mt][jt] = (f32x4){0.f, 0.f, 0.f, 0.f};

        #pragma unroll
        for (int kt = 0; kt < 4; ++kt) {
            bf16x8 bh[2], bl[2];
            #pragma unroll
            for (int jt = 0; jt < 2; ++jt) {
                int j = jbase + jt * 16 + lrow;
                bh[jt] = *(const bf16x8*)&WH[j * FDIM + kt * 32 + k0];
                bl[jt] = *(const bf16x8*)&WL[j * FDIM + kt * 32 + k0];
            }
            #pragma unroll
            for (int mt = 0; mt < 4; ++mt) {
                int off = aoff(rbase + mt * 16 + lrow, kt * 32 + k0);
                bf16x8 ah = *(const bf16x8*)&Ahi[off];
                bf16x8 al = *(const bf16x8*)&Alo[off];
                #pragma unroll
                for (int jt = 0; jt < 2; ++jt) {
                    acc[mt][jt] = __builtin_amdgcn_mfma_f32_16x16x32_bf16(ah, bh[jt], acc[mt][jt], 0, 0, 0);
                    acc[mt][jt] = __builtin_amdgcn_mfma_f32_16x16x32_bf16(ah, bl[jt], acc[mt][jt], 0, 0, 0);
                    acc[mt][jt] = __builtin_amdgcn_mfma_f32_16x16x32_bf16(al, bh[jt], acc[mt][jt], 0, 0, 0);
                }
            }
        }

        if (L == 0) {
            __syncthreads();   // all waves done reading layer-0 activations
            #pragma unroll
            for (int mt = 0; mt < 4; ++mt)
                #pragma unroll
                for (int jt = 0; jt < 2; ++jt)
                    #pragma unroll
                    for (int r = 0; r < 4; ++r) {
                        int row = rbase + mt * 16 + (lane >> 4) * 4 + r;
                        int col = jbase + jt * 16 + lrow;
                        float s = silu_fast(acc[mt][jt][r]);
                        unsigned u = __float_as_uint(s);
                        unsigned hm = u & 0xFFFF0000u;
                        float l = s - __uint_as_float(hm);
                        int off = aoff(row, col);
                        Ahi[off] = (unsigned short)(u >> 16);
                        Alo[off] = (unsigned short)(__float_as_uint(l) >> 16);
                    }
            __syncthreads();
        }
    }

    // epilogue: out = v_att + h2
    #pragma unroll
    for (int mt = 0; mt < 4; ++mt)
        #pragma unroll
        for (int jt = 0; jt < 2; ++jt) {
            int row0 = rbase + mt * 16 + (lane >> 4) * 4;
            int col  = jbase + jt * 16 + lrow;
            float* p = out + (long)(n0 + row0) * FDIM + col;
            #pragma unroll
            for (int r = 0; r < 4; ++r) {
                int row = row0 + r;
                float vatt = att_s[row] * wv_s[idx_s[row] * FDIM + col];
                p[r * FDIM] = acc[mt][jt][r] + vatt;
            }
        }
}

// ---------------------------------------------------------------------------
extern "C" void kernel_launch(void* const* d_in, const int* in_sizes, int n_in,
                              void* d_out, int out_size, void* d_ws, size_t ws_size,
                              hipStream_t stream) {
    const float* onehot = (const float*)d_in[0];
    const float* psi    = (const float*)d_in[1];
    const float* Wq     = (const float*)d_in[2];
    const float* Wk     = (const float*)d_in[3];
    const float* Wv     = (const float*)d_in[4];
    const float* W1     = (const float*)d_in[5];
    const float* W2     = (const float*)d_in[6];
    const int*   seg    = (const int*)d_in[7];
    float*       out    = (float*)d_out;

    // workspace layout
    char* ws = (char*)d_ws;
    float*          denom = (float*)ws;                              // 8192 f
    float*          T     = (float*)(ws + 32768);                    // 256 f
    int*            z     = (int*)(ws + 33792);                      // N i32
    float*          y     = (float*)(ws + 33792 + NATOMS * 4);       // N f32
    unsigned short* Whi   = (unsigned short*)(ws + 33792 + NATOMS * 8);            // 2*128*128 u16
    unsigned short* Wlo   = (unsigned short*)(ws + 33792 + NATOMS * 8 + 65536);    // 2*128*128 u16

    hipMemsetAsync(denom, 0, NG * sizeof(float), stream);

    table_kernel<<<1, 256, 0, stream>>>(Wq, Wk, T);
    wsplit_kernel<<<(2 * FDIM * FDIM) / 256, 256, 0, stream>>>(W1, W2, Whi, Wlo);

    {
        const int total4 = NATOMS * NELEM / 4;
        int blocks = (total4 + 255) / 256;
        zscan_kernel<<<blocks, 256, 0, stream>>>((const float4*)onehot, z);
    }

    ydenom_kernel<<<NATOMS / 256, 256, 0, stream>>>(seg, psi, T, z, y, denom);

    mlp_kernel<<<NATOMS / 128, 512, 0, stream>>>(seg, psi, y, denom, Wv, Whi, Wlo, out);
}